// Round 1
// baseline (182.841 us; speedup 1.0000x reference)
//
#include <hip/hip_runtime.h>
#include <math.h>

#define PI_F 3.14159265358979323846f
// swizzles: XOR bank-index bits with higher address bits (bijective, both sides)
#define SWZ16(i) ((i) ^ (((i) >> 4) & 7))   // used for t1 tiles in branch kernel
#define SWZ8(i)  ((i) ^ (((i) >> 3) & 7))   // used for Wd tile in down-proj

// ---------------- Kernel 0: build circular-conv tables from complex spectral weights --
// KK[a][b][c] = (1/S^2) * sum_{u<S, v<=S/2} m_v * ( wr*cos(2pi(ua+vb)/S) - wi*sin(...) )
__global__ __launch_bounds__(256) void build_tables(
    const float* __restrict__ cw_x, const float* __restrict__ cw_z,
    float* __restrict__ KKx, float* __restrict__ KKz)
{
    int tid = blockIdx.x * 256 + threadIdx.x;
    if (tid < 2048) {                    // X branch: S=16, V=9
        int c = tid & 7;
        int ab = tid >> 3;               // a*16+b
        int a = ab >> 4, b = ab & 15;
        float acc = 0.f;
        for (int u = 0; u < 16; ++u) {
            for (int v = 0; v < 9; ++v) {
                float m = (v == 0 || v == 8) ? 1.f : 2.f;
                int ph = (u * a + v * b) & 15;
                float th = (2.f * PI_F / 16.f) * (float)ph;
                float sn, cs;
                sincosf(th, &sn, &cs);
                const float* wp = cw_x + (size_t)((u * 9 + v) * 8 + c) * 2;
                acc += m * (wp[0] * cs - wp[1] * sn);
            }
        }
        KKx[ab * 8 + c] = acc * (1.f / 256.f);
    } else if (tid < 2048 + 512) {       // Z branch: S=8, V=5
        int e = tid - 2048;
        int c = e & 7;
        int ab = e >> 3;                 // a*8+b
        int a = ab >> 3, b = ab & 7;
        float acc = 0.f;
        for (int u = 0; u < 8; ++u) {
            for (int v = 0; v < 5; ++v) {
                float m = (v == 0 || v == 4) ? 1.f : 2.f;
                int ph = (u * a + v * b) & 7;
                float th = (2.f * PI_F / 8.f) * (float)ph;
                float sn, cs;
                sincosf(th, &sn, &cs);
                const float* wp = cw_z + (size_t)((u * 5 + v) * 8 + c) * 2;
                acc += m * (wp[0] * cs - wp[1] * sn);
            }
        }
        KKz[ab * 8 + c] = acc * (1.f / 64.f);
    }
}

// ---------------- Kernel 1: h = x @ Wd + bd  (81920 x 768 @ 768 x 8) ----------------
// 16 rows/block; each 16-lane group owns a row; Wd staged swizzled in LDS.
__global__ __launch_bounds__(256) void down_proj(
    const float* __restrict__ x, const float* __restrict__ Wd,
    const float* __restrict__ bd, float* __restrict__ h)
{
    __shared__ float4 wds[1536];                 // 768 rows x 8ch = 1536 float4, 24KB
    int t = threadIdx.x;
    const float4* Wd4 = (const float4*)Wd;
    #pragma unroll
    for (int j = 0; j < 6; ++j) {
        int i = t + 256 * j;
        wds[SWZ8(i)] = Wd4[i];
    }
    __syncthreads();

    int lane = t & 63;
    int wave = t >> 6;
    int sub  = lane >> 4;
    int l    = lane & 15;
    int row  = blockIdx.x * 16 + wave * 4 + sub;

    const float4* xr = (const float4*)x + (size_t)row * 192;
    float a0=0.f,a1=0.f,a2=0.f,a3=0.f,a4=0.f,a5=0.f,a6=0.f,a7=0.f;
    #pragma unroll
    for (int j = 0; j < 12; ++j) {
        float4 v = xr[l + 16 * j];
        int k0 = (l + 16 * j) * 4;
        float xv[4] = {v.x, v.y, v.z, v.w};
        #pragma unroll
        for (int e = 0; e < 4; ++e) {
            int f4 = (k0 + e) * 2;               // even
            int sw = SWZ8(f4);
            float4 w0 = wds[sw];
            float4 w1 = wds[sw ^ 1];             // SWZ8(f4+1) == SWZ8(f4)^1 (f4 even)
            a0 += xv[e] * w0.x;  a1 += xv[e] * w0.y;
            a2 += xv[e] * w0.z;  a3 += xv[e] * w0.w;
            a4 += xv[e] * w1.x;  a5 += xv[e] * w1.y;
            a6 += xv[e] * w1.z;  a7 += xv[e] * w1.w;
        }
    }
    // reduce across the 16-lane group
    #pragma unroll
    for (int off = 1; off < 16; off <<= 1) {
        a0 += __shfl_xor(a0, off, 64);  a1 += __shfl_xor(a1, off, 64);
        a2 += __shfl_xor(a2, off, 64);  a3 += __shfl_xor(a3, off, 64);
        a4 += __shfl_xor(a4, off, 64);  a5 += __shfl_xor(a5, off, 64);
        a6 += __shfl_xor(a6, off, 64);  a7 += __shfl_xor(a7, off, 64);
    }
    if (l == 0) {
        float4* hp = (float4*)h + (size_t)row * 2;
        hp[0] = make_float4(a0 + bd[0], a1 + bd[1], a2 + bd[2], a3 + bd[3]);
        hp[1] = make_float4(a4 + bd[4], a5 + bd[5], a6 + bd[6], a7 + bd[7]);
    }
}

// ---------------- Kernel 2: branch (LN1 -> circular conv -> LN2 -> MLP -> +raw) ------
// grid: blocks 0..63 = Z (4 batches x 64 tokens each), 64..319 = X (1 batch x 256 tok)
__global__ __launch_bounds__(256) void branch_kernel(
    const float* __restrict__ h,
    const float* __restrict__ KKx, const float* __restrict__ KKz,
    const float* __restrict__ g1v, const float* __restrict__ b1v,
    const float* __restrict__ g2v, const float* __restrict__ b2v,
    const float* __restrict__ W1, const float* __restrict__ b1m,
    const float* __restrict__ W2, const float* __restrict__ b2m,
    float* __restrict__ cat)
{
    __shared__ float4 t1s[512];   // 8KB: X: 256 tok x 2 f4 (swz); Z: 4 x 64 tok x 2 f4
    __shared__ float4 kks[512];   // 8KB: X table (or first 128 = Z table)
    __shared__ float sW1[128], sW2[128], sB1[16], sB2[8];
    __shared__ float sG1[8], sH1[8], sG2[8], sH2[8];

    int t = threadIdx.x;
    int bid = blockIdx.x;
    bool isX = (bid >= 64);

    if (t < 128) { sW1[t] = W1[t]; sW2[t] = W2[t]; }
    if (t < 16)  sB1[t] = b1m[t];
    if (t < 8) { sB2[t] = b2m[t]; sG1[t] = g1v[t]; sH1[t] = b1v[t]; sG2[t] = g2v[t]; sH2[t] = b2v[t]; }

    int rowidx;
    if (isX) {
        rowidx = (bid - 64) * 320 + 64 + t;
    } else {
        int w = t >> 6, tz = t & 63;
        rowidx = (bid * 4 + w) * 320 + tz;
    }
    const float4* hp = (const float4*)h + (size_t)rowidx * 2;
    float4 r0 = hp[0], r1 = hp[1];

    if (isX) {
        const float4* K4 = (const float4*)KKx;
        kks[t] = K4[t];  kks[t + 256] = K4[t + 256];
    } else {
        if (t < 128) kks[t] = ((const float4*)KKz)[t];
    }
    __syncthreads();   // params + kks visible

    float raw[8] = {r0.x, r0.y, r0.z, r0.w, r1.x, r1.y, r1.z, r1.w};
    float mean = 0.f;
    #pragma unroll
    for (int c = 0; c < 8; ++c) mean += raw[c];
    mean *= 0.125f;
    float var = 0.f;
    #pragma unroll
    for (int c = 0; c < 8; ++c) { float d = raw[c] - mean; var += d * d; }
    var *= 0.125f;
    float inv = rsqrtf(var + 1e-5f);
    float t1[8];
    #pragma unroll
    for (int c = 0; c < 8; ++c) t1[c] = (raw[c] - mean) * inv * sG1[c] + sH1[c];

    int base, i0;
    if (isX) { base = 0; i0 = 2 * t; }
    else     { int w = t >> 6, tz = t & 63; base = w * 128; i0 = 2 * tz; }
    t1s[base + SWZ16(i0)]     = make_float4(t1[0], t1[1], t1[2], t1[3]);
    t1s[base + SWZ16(i0 + 1)] = make_float4(t1[4], t1[5], t1[6], t1[7]);
    __syncthreads();   // t1s visible

    float s0=0.f,s1=0.f,s2=0.f,s3=0.f,s4=0.f,s5=0.f,s6=0.f,s7=0.f;
    if (isX) {
        int p = t >> 4, q = t & 15;
        for (int da = 0; da < 16; ++da) {
            int qp = (q - da) & 15;
            #pragma unroll
            for (int db = 0; db < 16; ++db) {
                int pp = (p - db) & 15;
                int si = (pp * 16 + qp) * 2;            // even
                float4 v0 = t1s[SWZ16(si)];
                float4 v1 = t1s[SWZ16(si + 1)];
                int kb = (da * 16 + db) * 2;
                float4 k0 = kks[kb], k1 = kks[kb + 1];
                s0 += k0.x * v0.x;  s1 += k0.y * v0.y;
                s2 += k0.z * v0.z;  s3 += k0.w * v0.w;
                s4 += k1.x * v1.x;  s5 += k1.y * v1.y;
                s6 += k1.z * v1.z;  s7 += k1.w * v1.w;
            }
        }
    } else {
        int w = t >> 6, tz = t & 63;
        int p = tz >> 3, q = tz & 7;
        int tb = w * 128;
        for (int da = 0; da < 8; ++da) {
            int qp = (q - da) & 7;
            #pragma unroll
            for (int db = 0; db < 8; ++db) {
                int pp = (p - db) & 7;
                int si = (pp * 8 + qp) * 2;             // even
                float4 v0 = t1s[tb + SWZ16(si)];
                float4 v1 = t1s[tb + SWZ16(si + 1)];
                int kb = (da * 8 + db) * 2;
                float4 k0 = kks[kb], k1 = kks[kb + 1];
                s0 += k0.x * v0.x;  s1 += k0.y * v0.y;
                s2 += k0.z * v0.z;  s3 += k0.w * v0.w;
                s4 += k1.x * v1.x;  s5 += k1.y * v1.y;
                s6 += k1.z * v1.z;  s7 += k1.w * v1.w;
            }
        }
    }

    float sarr[8] = {s0, s1, s2, s3, s4, s5, s6, s7};
    float m2 = 0.f;
    #pragma unroll
    for (int c = 0; c < 8; ++c) m2 += sarr[c];
    m2 *= 0.125f;
    float v2 = 0.f;
    #pragma unroll
    for (int c = 0; c < 8; ++c) { float d = sarr[c] - m2; v2 += d * d; }
    v2 *= 0.125f;
    float inv2 = rsqrtf(v2 + 1e-5f);
    float t2[8];
    #pragma unroll
    for (int c = 0; c < 8; ++c) t2[c] = (sarr[c] - m2) * inv2 * sG2[c] + sH2[c];

    float hm[16];
    #pragma unroll
    for (int j = 0; j < 16; ++j) {
        float acc = sB1[j];
        #pragma unroll
        for (int c = 0; c < 8; ++c) acc += t2[c] * sW1[c * 16 + j];
        hm[j] = 0.5f * acc * (1.f + erff(acc * 0.70710678118654752f));  // exact GELU
    }
    float o[8];
    #pragma unroll
    for (int c = 0; c < 8; ++c) {
        float acc = sB2[c];
        #pragma unroll
        for (int j = 0; j < 16; ++j) acc += hm[j] * sW2[j * 8 + c];
        o[c] = acc + raw[c];
    }
    float4* cp = (float4*)cat + (size_t)rowidx * 2;
    cp[0] = make_float4(o[0], o[1], o[2], o[3]);
    cp[1] = make_float4(o[4], o[5], o[6], o[7]);
}

// ---------------- Kernel 3: out = cat @ Wu + bu  (81920 x 8 @ 8 x 768) --------------
// 16 rows/block, 192 threads; Wu column-chunk held in registers (8 x float4)/thread.
__global__ __launch_bounds__(192) void up_proj(
    const float* __restrict__ cat, const float* __restrict__ Wu,
    const float* __restrict__ bu, float* __restrict__ out)
{
    __shared__ float4 wus[1536];   // 24KB: Wu[c][0..767] as f4: wus[c*192 + f]
    __shared__ float crow[128];    // 16 rows x 8 ch
    int t = threadIdx.x;
    const float4* Wu4 = (const float4*)Wu;
    #pragma unroll
    for (int j = 0; j < 8; ++j) wus[t + 192 * j] = Wu4[t + 192 * j];
    int row0 = blockIdx.x * 16;
    if (t < 128) crow[t] = cat[(size_t)row0 * 8 + t];
    __syncthreads();

    float4 wr[8];
    #pragma unroll
    for (int c = 0; c < 8; ++c) wr[c] = wus[c * 192 + t];
    float4 bv = ((const float4*)bu)[t];

    float4* outp = (float4*)out + (size_t)row0 * 192 + t;
    #pragma unroll
    for (int r = 0; r < 16; ++r) {
        const float* cr = &crow[r * 8];
        float4 acc = bv;
        #pragma unroll
        for (int c = 0; c < 8; ++c) {
            float cv = cr[c];
            acc.x += cv * wr[c].x;  acc.y += cv * wr[c].y;
            acc.z += cv * wr[c].z;  acc.w += cv * wr[c].w;
        }
        outp[(size_t)r * 192] = acc;
    }
}

extern "C" void kernel_launch(void* const* d_in, const int* in_sizes, int n_in,
                              void* d_out, int out_size, void* d_ws, size_t ws_size,
                              hipStream_t stream)
{
    (void)in_sizes; (void)n_in; (void)out_size; (void)ws_size;
    const float* x    = (const float*)d_in[0];
    const float* Wd   = (const float*)d_in[1];
    const float* bd   = (const float*)d_in[2];
    const float* cw_x = (const float*)d_in[3];
    const float* cw_z = (const float*)d_in[4];
    const float* g1   = (const float*)d_in[5];
    const float* h1   = (const float*)d_in[6];
    const float* g2   = (const float*)d_in[7];
    const float* h2   = (const float*)d_in[8];
    const float* W1   = (const float*)d_in[9];
    const float* b1   = (const float*)d_in[10];
    const float* W2   = (const float*)d_in[11];
    const float* b2   = (const float*)d_in[12];
    const float* Wu   = (const float*)d_in[13];
    const float* bu   = (const float*)d_in[14];
    float* out = (float*)d_out;

    float* h   = (float*)d_ws;          // 655360 floats
    float* cat = h + 655360;            // 655360 floats
    float* KKx = cat + 655360;          // 2048 floats
    float* KKz = KKx + 2048;            // 512 floats

    hipLaunchKernelGGL(build_tables, dim3(10), dim3(256), 0, stream, cw_x, cw_z, KKx, KKz);
    hipLaunchKernelGGL(down_proj,    dim3(5120), dim3(256), 0, stream, x, Wd, bd, h);
    hipLaunchKernelGGL(branch_kernel, dim3(320), dim3(256), 0, stream,
                       h, KKx, KKz, g1, h1, g2, h2, W1, b1, W2, b2, cat);
    hipLaunchKernelGGL(up_proj,      dim3(5120), dim3(192), 0, stream, cat, Wu, bu, out);
}